// Round 10
// baseline (110.926 us; speedup 1.0000x reference)
//
#include <hip/hip_runtime.h>

// Head: single-head causal attention. B=4, T=2048, D=1024, H=64. fp32 in/out.
// R10: qkv single-barrier restructure -- stage the ENTIRE 16x1024 x-tile to
// LDS (bf16, stride 1032 -> 2-way-free b128 reads), ONE __syncthreads, then
// a barrier-free 32-group MFMA run the compiler can pipeline (R9 paid 16
// full vmcnt(0) barrier drains per block at 2 blocks/CU).
// wt / attn_partial / merge unchanged (controls).
//
// ws layout (bytes):
//   [0,        393216)   wtf   bf16 [12][128][16][8]   (fragment-ordered W)
//   [393216,  1441792)   qf    bf16 [512][8][16][8]    (fragment-ordered Q)
//   [1441792, 2490368)   kf    bf16 [512][8][16][8]
//   [2490368, 3538944)   vf    bf16 [4][32][4][8][16][8]
//   [3538944, 12451840)  Opart bf16 [4352][16][64]     (gid-indexed)
//   [12451840,12730368)  mpart fp32 [4352][16]
//   [12730368,13008896)  lpart fp32 [4352][16]

typedef __attribute__((ext_vector_type(8))) __bf16 bf16x8;
typedef __attribute__((ext_vector_type(4))) float floatx4;

union BF8 {
    bf16x8 v;
    unsigned short s[8];
    uint4 u;
};
union BF4 {
    unsigned short s[4];
    unsigned long long ull;
};

__device__ inline unsigned short f2bf(float f) {
    unsigned int u = __float_as_uint(f);
    unsigned int r = (u + 0x7fffu + ((u >> 16) & 1u)) >> 16;
    return (unsigned short)r;
}
__device__ inline float bf2f(unsigned short s) {
    unsigned int u = ((unsigned int)s) << 16;
    return __uint_as_float(u);
}

// ---------------------------------------------------------------------------
// Kernel 0: W -> wtf fragment layout (unchanged). Grid 48 = 3 x 16.
// ---------------------------------------------------------------------------
__global__ __launch_bounds__(256) void wt_kernel(const float* __restrict__ Wq,
                                                 const float* __restrict__ Wk,
                                                 const float* __restrict__ Wv,
                                                 unsigned short* __restrict__ wtf) {
    __shared__ __align__(16) unsigned short lt[64 * 72];
    const int tid = threadIdx.x;
    const int sel = blockIdx.x >> 4;
    const int kb = blockIdx.x & 15;
    const float* W = (sel == 0) ? Wq : (sel == 1) ? Wk : Wv;

    const int h = tid & 63;
    const int kr = tid >> 6;
#pragma unroll
    for (int i = 0; i < 16; ++i) {
        const int kkl = kr + i * 4;
        lt[kkl * 72 + h] = f2bf(W[(size_t)(kb * 64 + kkl) * 64 + h]);
    }
    __syncthreads();

#pragma unroll
    for (int s = 0; s < 2; ++s) {
        const int seg = tid + s * 256;
        const int l16 = seg & 15;
        const int rest = seg >> 4;
        const int ko = rest & 7;
        const int hb = rest >> 3;
        const int hh = hb * 16 + l16;
        BF8 o;
#pragma unroll
        for (int j = 0; j < 8; ++j) o.s[j] = lt[(ko * 8 + j) * 72 + hh];
        const int nblk = sel * 4 + hb;
        const int koct = kb * 8 + ko;
        *(uint4*)(wtf + ((size_t)nblk * 128 + koct) * 128 + l16 * 8) = o.u;
    }
}

// ---------------------------------------------------------------------------
// Kernel 1: QKV projection, single-barrier. Grid 512 m-tiles(16 rows) x 256
// thr / 4 waves; wave w covers cols w*48..w*48+47 (192 = q64|k64|v64).
// Stage whole 16x1024 x-tile fp32->bf16 into LDS stride 1032 (16 indep
// float4 loads/thread), ONE sync, then 32 kst-groups of
// (ds_read_b128 + 3 wtf 256B loads + 3 MFMA) with no barriers.
// Epilogue: fragment-layout qf/kf/vf via LDS transpose (unchanged R9).
// ---------------------------------------------------------------------------
__global__ __launch_bounds__(256) void qkv_kernel(const float* __restrict__ x,
                                                  const unsigned short* __restrict__ wtf,
                                                  unsigned short* __restrict__ qf,
                                                  unsigned short* __restrict__ kf,
                                                  unsigned short* __restrict__ vf) {
    __shared__ __align__(16) unsigned short lxs[16 * 1032];
    __shared__ __align__(16) unsigned short lt[16 * 200];
    __shared__ __align__(16) unsigned short vtile[64 * 24];
    const int tid = threadIdx.x;
    const int w = tid >> 6;  // col-group: 48 cols each
    const int lane = tid & 63;
    const int quad = lane >> 4;
    const int l16 = lane & 15;
    const int m0 = blockIdx.x * 16;
    const int b = m0 >> 11;

    // ---- stage whole x-tile: thread = (row tid>>4, 16 float4 slots) ----
    {
        const int srow = tid >> 4;
        const int sc = tid & 15;
        const float* xp = x + (size_t)(m0 + srow) * 1024 + sc * 4;
        unsigned short* lp = &lxs[srow * 1032 + sc * 4];
#pragma unroll
        for (int i = 0; i < 16; ++i) {
            float4 v = *(const float4*)(xp + i * 64);
            BF4 b_;
            b_.s[0] = f2bf(v.x); b_.s[1] = f2bf(v.y);
            b_.s[2] = f2bf(v.z); b_.s[3] = f2bf(v.w);
            *(unsigned long long*)(lp + i * 64) = b_.ull;
        }
    }
    __syncthreads();

    floatx4 acc[3];
#pragma unroll
    for (int i = 0; i < 3; ++i) acc[i] = (floatx4)(0.0f);

    const unsigned short* lpa = &lxs[l16 * 1032 + quad * 8];
#pragma unroll
    for (int kg = 0; kg < 32; ++kg) {
        const int koct = kg * 4 + quad;
        BF8 a;
        a.u = *(const uint4*)(lpa + kg * 32);
#pragma unroll
        for (int nt = 0; nt < 3; ++nt) {
            const int nb = w * 3 + nt;
            BF8 bfr;
            bfr.u = *(const uint4*)(wtf + ((size_t)nb * 128 + koct) * 128 + l16 * 8);
            acc[nt] = __builtin_amdgcn_mfma_f32_16x16x32_bf16(a.v, bfr.v, acc[nt], 0, 0, 0);
        }
    }
    __syncthreads();  // lxs dead; lt/vtile reuse region is separate but order anyway

    // epilogue: stash C-tiles. cols 0..127 (q,k) -> lt row-major; 128..191 (v)
    // -> vtile (4 consecutive t packed per lane).
#pragma unroll
    for (int nt = 0; nt < 3; ++nt) {
        const int ngl = w * 48 + nt * 16;
        if (ngl < 128) {
#pragma unroll
            for (int r = 0; r < 4; ++r)
                lt[(quad * 4 + r) * 200 + ngl + l16] = f2bf(acc[nt][r]);
        } else {
            BF4 pk;
#pragma unroll
            for (int r = 0; r < 4; ++r) pk.s[r] = f2bf(acc[nt][r]);
            *(unsigned long long*)&vtile[(ngl - 128 + l16) * 24 + quad * 4] = pk.ull;
        }
    }
    __syncthreads();

    // q/k emission: 256 segs of 16B; 16 consecutive tids -> 256B contiguous.
    {
        const int row = tid & 15;
        const int koct = tid >> 4;  // 0..15
        uint4 seg = *(const uint4*)&lt[row * 200 + koct * 8];
        const size_t tile = blockIdx.x;  // = b*128 + qt
        if (koct < 8)
            *(uint4*)(qf + tile * 1024 + koct * 128 + row * 8) = seg;
        else
            *(uint4*)(kf + tile * 1024 + (koct - 8) * 128 + row * 8) = seg;
    }
    // v emission: 128 segs of 16B (8 consecutive t at fixed h).
    if (tid < 128) {
        const int h = tid >> 1;
        const int sg = tid & 1;
        uint4 seg = *(const uint4*)&vtile[h * 24 + sg * 8];
        const int jt = (m0 & 2047) >> 6;
        const int koct = ((m0 & 63) >> 3) + sg;
        *(uint4*)(vf + (((size_t)(b * 32 + jt) * 4 + (h >> 4)) * 8 + koct) * 128 +
                  (h & 15) * 8) = seg;
    }
}

// ---------------------------------------------------------------------------
// Kernel 2: flash pass A, compact triangular grid (unchanged R9).
// ---------------------------------------------------------------------------
__global__ __launch_bounds__(256) void attn_partial(const unsigned short* __restrict__ qf,
                                                    const unsigned short* __restrict__ kf,
                                                    const unsigned short* __restrict__ vf,
                                                    unsigned short* __restrict__ Opart,
                                                    float* __restrict__ mpart,
                                                    float* __restrict__ lpart) {
    __shared__ __align__(16) unsigned short lds_p[4 * 16 * 72];
    const int tid = threadIdx.x;
    const int w = tid >> 6;
    const int lane = tid & 63;
    const int quad = lane >> 4;
    const int l16 = lane & 15;
    const int gid = blockIdx.x * 4 + w;  // 0..4351
    const int b = gid / 1088;
    const int rem = gid - b * 1088;
    int g = (int)((sqrtf((float)(4 * rem + 1)) - 1.0f) * 0.5f);
    while (4 * (g + 1) * (g + 2) <= rem) ++g;
    while (4 * g * (g + 1) > rem) --g;
    const int off = rem - 4 * g * (g + 1);
    const int nc = g + 1;
    const int qti = off / nc;
    const int kc = off - qti * nc;
    const int qt = g * 8 + qti;
    const int r0 = qt * 16;

    BF8 aq[2];
    {
        const unsigned short* qtile = qf + (size_t)(b * 128 + qt) * 1024;
        aq[0].u = *(const uint4*)(qtile + lane * 8);
        aq[1].u = *(const uint4*)(qtile + 512 + lane * 8);
    }

    floatx4 oacc[4];
#pragma unroll
    for (int nt = 0; nt < 4; ++nt) oacc[nt] = (floatx4)(0.0f);
    float m_i[4], l_i[4];
#pragma unroll
    for (int r = 0; r < 4; ++r) { m_i[r] = -3.0e38f; l_i[r] = 0.0f; }

    unsigned short* myp = lds_p + w * (16 * 72);

    for (int t = 0; t < 2; ++t) {
        const int j0 = kc * 128 + t * 64;
        if (j0 > r0 + 15) break;

        floatx4 s[4];
#pragma unroll
        for (int nt = 0; nt < 4; ++nt) s[nt] = (floatx4)(0.0f);
#pragma unroll
        for (int kst = 0; kst < 2; ++kst) {
#pragma unroll
            for (int nt = 0; nt < 4; ++nt) {
                BF8 bk;
                bk.u = *(const uint4*)(kf + (size_t)(b * 128 + (j0 >> 4) + nt) * 1024 +
                                       kst * 512 + lane * 8);
                s[nt] = __builtin_amdgcn_mfma_f32_16x16x32_bf16(aq[kst].v, bk.v, s[nt], 0, 0, 0);
            }
        }

        float sv[4][4];
        const bool masked = (j0 + 63 > r0);
#pragma unroll
        for (int nt = 0; nt < 4; ++nt)
#pragma unroll
            for (int r = 0; r < 4; ++r) {
                float val = s[nt][r] * 0.125f;
                if (masked) {
                    int key = j0 + nt * 16 + l16;
                    int qr = r0 + quad * 4 + r;
                    if (key > qr) val = -3.0e38f;
                }
                sv[nt][r] = val;
            }

        float alpha[4];
#pragma unroll
        for (int r = 0; r < 4; ++r) {
            float mx = fmaxf(fmaxf(sv[0][r], sv[1][r]), fmaxf(sv[2][r], sv[3][r]));
            mx = fmaxf(mx, __shfl_xor(mx, 1));
            mx = fmaxf(mx, __shfl_xor(mx, 2));
            mx = fmaxf(mx, __shfl_xor(mx, 4));
            mx = fmaxf(mx, __shfl_xor(mx, 8));
            float mn = fmaxf(m_i[r], mx);
            alpha[r] = __expf(m_i[r] - mn);
            m_i[r] = mn;
        }
        float rs[4] = {0.f, 0.f, 0.f, 0.f};
#pragma unroll
        for (int nt = 0; nt < 4; ++nt)
#pragma unroll
            for (int r = 0; r < 4; ++r) {
                float p = __expf(sv[nt][r] - m_i[r]);
                sv[nt][r] = p;
                rs[r] += p;
            }
#pragma unroll
        for (int r = 0; r < 4; ++r) {
            float t2 = rs[r];
            t2 += __shfl_xor(t2, 1);
            t2 += __shfl_xor(t2, 2);
            t2 += __shfl_xor(t2, 4);
            t2 += __shfl_xor(t2, 8);
            l_i[r] = l_i[r] * alpha[r] + t2;
        }
#pragma unroll
        for (int nt = 0; nt < 4; ++nt)
#pragma unroll
            for (int r = 0; r < 4; ++r) oacc[nt][r] *= alpha[r];

#pragma unroll
        for (int nt = 0; nt < 4; ++nt)
#pragma unroll
            for (int r = 0; r < 4; ++r)
                myp[(quad * 4 + r) * 72 + nt * 16 + l16] = f2bf(sv[nt][r]);

#pragma unroll
        for (int kst = 0; kst < 2; ++kst) {
            BF8 ap;
            ap.u = *(const uint4*)(myp + l16 * 72 + kst * 32 + quad * 8);
#pragma unroll
            for (int nt = 0; nt < 4; ++nt) {
                BF8 bv;
                bv.u = *(const uint4*)(vf + ((size_t)(b * 32 + (j0 >> 6)) * 4 + nt) * 1024 +
                                       kst * 512 + lane * 8);
                oacc[nt] = __builtin_amdgcn_mfma_f32_16x16x32_bf16(ap.v, bv.v, oacc[nt], 0, 0, 0);
            }
        }
    }

    const size_t ob = (size_t)gid * 1024;
#pragma unroll
    for (int nt = 0; nt < 4; ++nt)
#pragma unroll
        for (int r = 0; r < 4; ++r)
            Opart[ob + (quad * 4 + r) * 64 + nt * 16 + l16] = f2bf(oacc[nt][r]);
    if (l16 == 0) {
#pragma unroll
        for (int r = 0; r < 4; ++r) {
            mpart[gid * 16 + quad * 4 + r] = m_i[r];
            lpart[gid * 16 + quad * 4 + r] = l_i[r];
        }
    }
}

// ---------------------------------------------------------------------------
// Kernel 3: merge, flat online single pass (unchanged R9).
// ---------------------------------------------------------------------------
__global__ __launch_bounds__(256) void attn_merge(const unsigned short* __restrict__ Opart,
                                                  const float* __restrict__ mpart,
                                                  const float* __restrict__ lpart,
                                                  float* __restrict__ out) {
    const int e = blockIdx.x * 256 + threadIdx.x;
    const int col = e & 63;
    const int t = (e >> 6) & 2047;
    const int b = e >> 17;
    const int qt = t >> 4;
    const int row16 = t & 15;
    const int g = qt >> 3;
    const int nc = g + 1;
    const int base_id = b * 1088 + 4 * g * (g + 1) + (qt & 7) * nc;

    float M = -3.0e38f, L = 0.0f, O = 0.0f;
#pragma unroll 4
    for (int c = 0; c < nc; ++c) {
        const float m_c = mpart[(base_id + c) * 16 + row16];
        const float l_c = lpart[(base_id + c) * 16 + row16];
        const float o_c = bf2f(Opart[(size_t)(base_id + c) * 1024 + row16 * 64 + col]);
        const float Mn = fmaxf(M, m_c);
        const float a = __expf(M - Mn);
        const float ec = __expf(m_c - Mn);
        L = L * a + ec * l_c;
        O = O * a + ec * o_c;
        M = Mn;
    }
    out[e] = O / L;
}

extern "C" void kernel_launch(void* const* d_in, const int* in_sizes, int n_in,
                              void* d_out, int out_size, void* d_ws, size_t ws_size,
                              hipStream_t stream) {
    const float* x = (const float*)d_in[0];
    const float* Wq = (const float*)d_in[1];
    const float* Wk = (const float*)d_in[2];
    const float* Wv = (const float*)d_in[3];
    float* out = (float*)d_out;

    char* ws = (char*)d_ws;
    unsigned short* wtf = (unsigned short*)(ws);
    unsigned short* qf = (unsigned short*)(ws + 393216);
    unsigned short* kf = (unsigned short*)(ws + 1441792);
    unsigned short* vf = (unsigned short*)(ws + 2490368);
    unsigned short* Opart = (unsigned short*)(ws + 3538944);
    float* mpart = (float*)(ws + 12451840ull);
    float* lpart = (float*)(ws + 12730368ull);

    hipLaunchKernelGGL(wt_kernel, dim3(48), dim3(256), 0, stream, Wq, Wk, Wv, wtf);
    hipLaunchKernelGGL(qkv_kernel, dim3(512), dim3(256), 0, stream, x, wtf, qf, kf, vf);
    hipLaunchKernelGGL(attn_partial, dim3(1088), dim3(256), 0, stream, qf, kf, vf, Opart, mpart, lpart);
    hipLaunchKernelGGL(attn_merge, dim3(2048), dim3(256), 0, stream, Opart, mpart, lpart, out);
}